// Round 1
// baseline (186.134 us; speedup 1.0000x reference)
//
#include <hip/hip_runtime.h>
#include <math.h>

#define NSLICES 4
#define HID 512
#define IN_FEAT 342
#define OUTD 311
#define BATCH 256

#define TO 64
#define TB 64
#define BK 32

// Per-batch cubic blend coefficients: slice s weight d[s].
// pscale = 4*phase; mu = frac(pscale); i1 = floor(pscale) mod 4.
// Wb = c0*W[i0]+c1*W[i1]+c2*W[i2]+c3*W[i3], i_k = (i1+k-1) mod 4,
// so d[(i1+k+3)&3] = c[k].
__device__ __forceinline__ void phase_coeffs(float phase, float d[4]) {
    float ps = (float)NSLICES * phase;
    float fl = floorf(ps);
    float mu = ps - fl;
    int i1 = ((int)fl) & 3;
    float mu2 = mu * mu, mu3 = mu2 * mu;
    float c[4];
    c[0] = -0.5f * mu3 + mu2 - 0.5f * mu;
    c[1] = 1.5f * mu3 - 2.5f * mu2 + 1.0f;
    c[2] = -1.5f * mu3 + 2.0f * mu2 + 0.5f * mu;
    c[3] = 0.5f * mu3 - 0.5f * mu2;
#pragma unroll
    for (int k = 0; k < 4; k++) d[(i1 + k + 3) & 3] = c[k];
}

// Y[(ks*4+s)*BATCH + b][o] = sum_{k in ks-range} W[s][o][k] * H[b][k]
// W: [4][M][K] row-major. H: [BATCH][lda] (first K cols used).
// Grid: (ceil(M/TO), BATCH/TB, 8)  z = s*2 + ks (2-way K split).
__global__ __launch_bounds__(256) void gemm_slices(
    const float* __restrict__ W, const float* __restrict__ H,
    float* __restrict__ Y, int M, int K, int lda, int nch_lo)
{
    __shared__ __align__(16) float Wt[BK][TO + 4];
    __shared__ __align__(16) float Ht[BK][TB + 4];

    const int z = blockIdx.z;
    const int s = z >> 1;
    const int ks = z & 1;
    const int o0 = blockIdx.x * TO;
    const int b0 = blockIdx.y * TB;
    const int k_begin = ks ? nch_lo * BK : 0;
    const int k_end = ks ? K : nch_lo * BK;

    const int tid = (int)threadIdx.x;
    const int tx = tid & 15;    // b-group: 4 batch cols each
    const int ty = tid >> 4;    // o-group: 4 out rows each (0..15)
    const int lr = tid >> 5;    // staging row 0..7
    const int lc = tid & 31;    // staging col 0..31

    const float* Wbase = W + ((size_t)s * M + o0) * K;
    const float* Hbase = H + (size_t)b0 * lda;

    float acc[4][4];
#pragma unroll
    for (int i = 0; i < 4; i++)
#pragma unroll
        for (int j = 0; j < 4; j++) acc[i][j] = 0.f;

    for (int k0 = k_begin; k0 < k_end; k0 += BK) {
        __syncthreads();
        const int gk = k0 + lc;
        const bool kin = (gk < K);
#pragma unroll
        for (int i = 0; i < 8; i++) {
            int r = lr + 8 * i;
            float v = 0.f;
            if (kin && (o0 + r) < M) v = Wbase[(size_t)r * K + gk];
            Wt[lc][r] = v;
        }
#pragma unroll
        for (int i = 0; i < 8; i++) {
            int b = lr + 8 * i;
            float v = kin ? Hbase[(size_t)b * lda + gk] : 0.f;
            Ht[lc][b] = v;
        }
        __syncthreads();
#pragma unroll
        for (int k = 0; k < BK; k++) {
            float4 wv4 = *(const float4*)(&Wt[k][ty << 2]);
            float4 hv4 = *(const float4*)(&Ht[k][tx << 2]);
            float wv[4] = {wv4.x, wv4.y, wv4.z, wv4.w};
            float hv[4] = {hv4.x, hv4.y, hv4.z, hv4.w};
#pragma unroll
            for (int i = 0; i < 4; i++)
#pragma unroll
                for (int j = 0; j < 4; j++)
                    acc[i][j] = fmaf(wv[i], hv[j], acc[i][j]);
        }
    }

    const int ob = o0 + (ty << 2);
#pragma unroll
    for (int j = 0; j < 4; j++) {
        int b = b0 + (tx << 2) + j;
        float v[4] = {acc[0][j], acc[1][j], acc[2][j], acc[3][j]};
        float* dst = Y + ((size_t)(ks * 4 + s) * BATCH + b) * M + ob;
        if (ob + 4 <= M) {
            *(float4*)dst = make_float4(v[0], v[1], v[2], v[3]);
        } else {
#pragma unroll
            for (int i = 0; i < 4; i++)
                if (ob + i < M) dst[i] = v[i];
        }
    }
}

// Hout[b][o] = act( sum_s d_s(b) * (Y[0][s][b][o] + Y[1][s][b][o] + bias[s][o]) )
// Grid: BATCH blocks x 256 threads.
__global__ __launch_bounds__(256) void blend_bias_act(
    const float* __restrict__ Y, const float* __restrict__ bias,
    const float* __restrict__ x, float* __restrict__ Hout,
    int M, int do_elu)
{
    const int b = blockIdx.x;
    const int tid = (int)threadIdx.x;
    float d[4];
    phase_coeffs(x[(size_t)b * (IN_FEAT + 1) + IN_FEAT], d);

    for (int o = tid; o < M; o += 256) {
        float v = 0.f;
#pragma unroll
        for (int s = 0; s < 4; s++) {
            float t = Y[((size_t)s * BATCH + b) * M + o]
                    + Y[((size_t)(4 + s) * BATCH + b) * M + o]
                    + bias[(size_t)s * M + o];
            v = fmaf(d[s], t, v);
        }
        if (do_elu) v = (v > 0.f) ? v : expm1f(v);
        Hout[(size_t)b * M + o] = v;
    }
}

extern "C" void kernel_launch(void* const* d_in, const int* in_sizes, int n_in,
                              void* d_out, int out_size, void* d_ws, size_t ws_size,
                              hipStream_t stream) {
    const float* x  = (const float*)d_in[0];   // [256][343]
    const float* W0 = (const float*)d_in[1];   // [4][512][342]
    const float* b0 = (const float*)d_in[2];   // [4][512]
    const float* W1 = (const float*)d_in[3];   // [4][512][512]
    const float* b1 = (const float*)d_in[4];   // [4][512]
    const float* W2 = (const float*)d_in[5];   // [4][311][512]
    const float* b2 = (const float*)d_in[6];   // [4][311]
    float* out = (float*)d_out;                // [256][311]

    float* yBuf = (float*)d_ws;                       // 2*4*256*512 floats (4 MB)
    float* hBuf = yBuf + (size_t)2 * 4 * BATCH * HID; // 256*512 floats (0.5 MB)

    // ---- layer 0: K=342, M=512, H = x (lda=343) ----
    {
        const int K = IN_FEAT, M = HID;
        const int nch = (K + BK - 1) / BK;        // 11
        const int nlo = (nch + 1) / 2;            // 6
        dim3 g((M + TO - 1) / TO, BATCH / TB, 8); // 8 x 4 x 8 = 256 blocks
        gemm_slices<<<g, 256, 0, stream>>>(W0, x, yBuf, M, K, IN_FEAT + 1, nlo);
        blend_bias_act<<<dim3(BATCH), 256, 0, stream>>>(yBuf, b0, x, hBuf, HID, 1);
    }
    // ---- layer 1: K=512, M=512, H = hBuf (lda=512) ----
    {
        const int K = HID, M = HID;
        const int nlo = ((K + BK - 1) / BK + 1) / 2; // 8
        dim3 g((M + TO - 1) / TO, BATCH / TB, 8);    // 256 blocks
        gemm_slices<<<g, 256, 0, stream>>>(W1, hBuf, yBuf, M, K, HID, nlo);
        blend_bias_act<<<dim3(BATCH), 256, 0, stream>>>(yBuf, b1, x, hBuf, HID, 1);
    }
    // ---- layer 2: K=512, M=311, H = hBuf (lda=512), out -> d_out ----
    {
        const int K = HID, M = OUTD;
        const int nlo = ((K + BK - 1) / BK + 1) / 2; // 8
        dim3 g((M + TO - 1) / TO, BATCH / TB, 8);    // 5 x 4 x 8 = 160 blocks
        gemm_slices<<<g, 256, 0, stream>>>(W2, hBuf, yBuf, M, K, HID, nlo);
        blend_bias_act<<<dim3(BATCH), 256, 0, stream>>>(yBuf, b2, x, out, OUTD, 0);
    }
}

// Round 2
// 133.040 us; speedup vs baseline: 1.3991x; 1.3991x over previous
//
#include <hip/hip_runtime.h>
#include <math.h>

#define NSLICES 4
#define HID 512
#define IN_FEAT 342
#define OUTD 311
#define BATCH 256
#define LDA0 352       // padded layer-0 activation row stride
#define BK 32
#define BKP 36         // padded LDS row stride (floats): 144B = 9 quads (odd) -> conflict-free

// ---------------- prep: pad x into H0[256][352], compute blend coeffs d[256][4] ----------
__global__ __launch_bounds__(128) void prep_kernel(const float* __restrict__ x,
                                                   float* __restrict__ H0,
                                                   float* __restrict__ dcoef)
{
    const int b = blockIdx.x;
    const float* xr = x + (size_t)b * (IN_FEAT + 1);
    float* hr = H0 + (size_t)b * LDA0;
    for (int k = threadIdx.x; k < LDA0; k += 128)
        hr[k] = (k < IN_FEAT) ? xr[k] : 0.f;
    if (threadIdx.x == 0) {
        float ps = 4.f * xr[IN_FEAT];
        float fl = floorf(ps);
        float mu = ps - fl;
        int i1 = ((int)fl) & 3;
        float mu2 = mu * mu, mu3 = mu2 * mu;
        float c0 = -0.5f * mu3 + mu2 - 0.5f * mu;
        float c1 = 1.5f * mu3 - 2.5f * mu2 + 1.0f;
        float c2 = -1.5f * mu3 + 2.0f * mu2 + 0.5f * mu;
        float c3 = 0.5f * mu3 - 0.5f * mu2;
        float d[4];
        d[(i1 + 3) & 3] = c0;
        d[i1]           = c1;
        d[(i1 + 1) & 3] = c2;
        d[(i1 + 2) & 3] = c3;
        float* dd = dcoef + b * 4;
        dd[0] = d[0]; dd[1] = d[1]; dd[2] = d[2]; dd[3] = d[3];
    }
}

// ---------------- GEMM: Y[(sp*4+s)*256 + b][o] = sum_{k in split sp} W[s][o][k]*H[b][k] ----
// 64(o) x 64(b) tile, BK=32, 256 threads, 4x4 outputs/thread via dot4.
// thread tx=tid&15 -> o = o0+tx+16i ; ty=tid>>4 -> b = b0+ty+16j
// Register-prefetch software pipeline: load tile t+1 while computing tile t.
struct WStage { float2 v[4]; };
struct HStage { float4 v[2]; };

__device__ __forceinline__ void load_w(WStage& st, const float* __restrict__ Wb,
                                       int o0, int M, int K, int k0, int tid)
{
#pragma unroll
    for (int t = 0; t < 4; t++) {
        int c = tid + 256 * t;
        int r = c >> 4, kh = c & 15;
        int row = o0 + r, k = k0 + kh * 2;
        float2 v = make_float2(0.f, 0.f);
        if (row < M) {
            const float* p = Wb + (size_t)row * K + k;
            if (k + 2 <= K)      v = *reinterpret_cast<const float2*>(p);
            else if (k < K)      v.x = p[0];
        }
        st.v[t] = v;
    }
}

__device__ __forceinline__ void load_h(HStage& st, const float* __restrict__ H,
                                       int b0, int lda, int k0, int tid)
{
#pragma unroll
    for (int t = 0; t < 2; t++) {
        int c = tid + 256 * t;
        int r = c >> 3, kq = c & 7;
        st.v[t] = *reinterpret_cast<const float4*>(H + (size_t)(b0 + r) * lda + k0 + kq * 4);
    }
}

__global__ __launch_bounds__(256) void gemm_tiled(
    const float* __restrict__ W, const float* __restrict__ H,
    float* __restrict__ Y, int M, int K, int lda, int nsplit)
{
    __shared__ __align__(16) float Ws[64 * BKP];
    __shared__ __align__(16) float Hs[64 * BKP];

    const int tid = (int)threadIdx.x;
    const int tx = tid & 15;
    const int ty = tid >> 4;
    const int o0 = blockIdx.x * 64;
    const int b0 = blockIdx.y * 64;
    const int z  = blockIdx.z;
    const int s  = z & 3;
    const int sp = z >> 2;

    const int Ktiles = (K + BK - 1) / BK;
    const int nt = (Ktiles + nsplit - 1) / nsplit;
    const int tbeg = sp * nt;
    const int tend = (tbeg + nt < Ktiles) ? (tbeg + nt) : Ktiles;

    const float* Wb = W + (size_t)s * M * K;

    float acc[4][4];
#pragma unroll
    for (int i = 0; i < 4; i++)
#pragma unroll
        for (int j = 0; j < 4; j++) acc[i][j] = 0.f;

    WStage wst; HStage hst;
    if (tbeg < tend) {
        load_w(wst, Wb, o0, M, K, tbeg * BK, tid);
        load_h(hst, H, b0, lda, tbeg * BK, tid);
    }

    for (int kt = tbeg; kt < tend; ++kt) {
        __syncthreads();
        // regs -> LDS
#pragma unroll
        for (int t = 0; t < 4; t++) {
            int c = tid + 256 * t;
            int r = c >> 4, kh = c & 15;
            *reinterpret_cast<float2*>(&Ws[r * BKP + kh * 2]) = wst.v[t];
        }
#pragma unroll
        for (int t = 0; t < 2; t++) {
            int c = tid + 256 * t;
            int r = c >> 3, kq = c & 7;
            *reinterpret_cast<float4*>(&Hs[r * BKP + kq * 4]) = hst.v[t];
        }
        // issue next tile's global loads (overlaps with compute below)
        if (kt + 1 < tend) {
            load_w(wst, Wb, o0, M, K, (kt + 1) * BK, tid);
            load_h(hst, H, b0, lda, (kt + 1) * BK, tid);
        }
        __syncthreads();
        // compute
#pragma unroll
        for (int kq = 0; kq < 8; ++kq) {
            float4 wv[4], hv[4];
#pragma unroll
            for (int i = 0; i < 4; i++)
                wv[i] = *reinterpret_cast<const float4*>(&Ws[(tx + 16 * i) * BKP + kq * 4]);
#pragma unroll
            for (int j = 0; j < 4; j++)
                hv[j] = *reinterpret_cast<const float4*>(&Hs[(ty + 16 * j) * BKP + kq * 4]);
#pragma unroll
            for (int i = 0; i < 4; i++)
#pragma unroll
                for (int j = 0; j < 4; j++) {
                    acc[i][j] = fmaf(wv[i].x, hv[j].x, acc[i][j]);
                    acc[i][j] = fmaf(wv[i].y, hv[j].y, acc[i][j]);
                    acc[i][j] = fmaf(wv[i].z, hv[j].z, acc[i][j]);
                    acc[i][j] = fmaf(wv[i].w, hv[j].w, acc[i][j]);
                }
        }
    }

    // epilogue: write partial plane (zeros if this split had no tiles)
    const int plane = sp * 4 + s;
#pragma unroll
    for (int j = 0; j < 4; j++) {
        int b = b0 + ty + 16 * j;
        float* dst = Y + ((size_t)plane * BATCH + b) * M;
#pragma unroll
        for (int i = 0; i < 4; i++) {
            int o = o0 + tx + 16 * i;
            if (o < M) dst[o] = acc[i][j];
        }
    }
}

// ---------------- blend: out[b][o] = act( sum_s d_s(b)*(sum_sp Y[sp,s,b,o] + bias_s[o]) ) --
__global__ __launch_bounds__(256) void blend_kernel(
    const float* __restrict__ Y, const float* __restrict__ bias,
    const float* __restrict__ dcoef, float* __restrict__ Hout,
    int M, int ldo, int nsplit, int do_elu)
{
    const int b = blockIdx.x;
    const float d0 = dcoef[b * 4 + 0];
    const float d1 = dcoef[b * 4 + 1];
    const float d2 = dcoef[b * 4 + 2];
    const float d3 = dcoef[b * 4 + 3];

    for (int o = (int)threadIdx.x; o < ldo; o += 256) {
        float v;
        if (o < M) {
            float t0 = 0.f, t1 = 0.f, t2 = 0.f, t3 = 0.f;
            for (int sp = 0; sp < nsplit; ++sp) {
                const float* base = Y + (((size_t)sp * 4) * BATCH + b) * M + o;
                t0 += base[0 * (size_t)BATCH * M];
                t1 += base[1 * (size_t)BATCH * M];
                t2 += base[2 * (size_t)BATCH * M];
                t3 += base[3 * (size_t)BATCH * M];
            }
            v = d0 * (t0 + bias[0 * M + o]) + d1 * (t1 + bias[1 * M + o])
              + d2 * (t2 + bias[2 * M + o]) + d3 * (t3 + bias[3 * M + o]);
            if (do_elu) v = (v > 0.f) ? v : expm1f(v);
        } else {
            v = 0.f;
        }
        Hout[(size_t)b * ldo + o] = v;
    }
}

extern "C" void kernel_launch(void* const* d_in, const int* in_sizes, int n_in,
                              void* d_out, int out_size, void* d_ws, size_t ws_size,
                              hipStream_t stream) {
    const float* x  = (const float*)d_in[0];
    const float* W0 = (const float*)d_in[1];
    const float* b0 = (const float*)d_in[2];
    const float* W1 = (const float*)d_in[3];
    const float* b1 = (const float*)d_in[4];
    const float* W2 = (const float*)d_in[5];
    const float* b2 = (const float*)d_in[6];
    float* out = (float*)d_out;

    // ws layout (floats): d[1024] | H0[256*352] | Ha[256*512] | Hb[256*512] | Y[nsplit*4*256*512]
    const size_t planeGroupF = (size_t)4 * BATCH * HID;             // one split's 4 slices
    const size_t baseF = 1024 + (size_t)BATCH * LDA0 + 2 * (size_t)BATCH * HID;
    int nsplit = 4;
    while (nsplit > 1 && (baseF + (size_t)nsplit * planeGroupF) * 4 > ws_size) nsplit >>= 1;

    float* dcoef = (float*)d_ws;
    float* H0 = dcoef + 1024;
    float* Ha = H0 + (size_t)BATCH * LDA0;
    float* Hb = Ha + (size_t)BATCH * HID;
    float* Y  = Hb + (size_t)BATCH * HID;

    prep_kernel<<<dim3(BATCH), 128, 0, stream>>>(x, H0, dcoef);

    // layer 0: M=512, K=342, lda=352
    gemm_tiled<<<dim3(HID / 64, BATCH / 64, 4 * nsplit), 256, 0, stream>>>(
        W0, H0, Y, HID, IN_FEAT, LDA0, nsplit);
    blend_kernel<<<dim3(BATCH), 256, 0, stream>>>(Y, b0, dcoef, Ha, HID, HID, nsplit, 1);

    // layer 1: M=512, K=512
    gemm_tiled<<<dim3(HID / 64, BATCH / 64, 4 * nsplit), 256, 0, stream>>>(
        W1, Ha, Y, HID, HID, HID, nsplit);
    blend_kernel<<<dim3(BATCH), 256, 0, stream>>>(Y, b1, dcoef, Hb, HID, HID, nsplit, 1);

    // layer 2: M=311, K=512
    gemm_tiled<<<dim3((OUTD + 63) / 64, BATCH / 64, 4 * nsplit), 256, 0, stream>>>(
        W2, Hb, Y, OUTD, HID, HID, nsplit);
    blend_kernel<<<dim3(BATCH), 256, 0, stream>>>(Y, b2, dcoef, out, OUTD, OUTD, nsplit, 0);
}

// Round 3
// 112.584 us; speedup vs baseline: 1.6533x; 1.1817x over previous
//
#include <hip/hip_runtime.h>
#include <math.h>

#define NSLICES 4
#define HID 512
#define IN_FEAT 342
#define OUTD 311
#define BATCH 256
#define KP0 352           // layer-0 padded K (11 chunks of 32)
#define MP2 320           // layer-2 padded M
#define XROW (IN_FEAT + 1)

typedef unsigned short u16;
typedef short bf16x8 __attribute__((ext_vector_type(8)));
typedef float f32x4 __attribute__((ext_vector_type(4)));

__device__ __forceinline__ u16 f2bf_rne(float v) {
    unsigned int x = __float_as_uint(v);
    unsigned int r = (x + 0x7fffu + ((x >> 16) & 1u)) >> 16;
    return (u16)r;
}
__device__ __forceinline__ float bf2f(u16 u) {
    return __uint_as_float(((unsigned int)u) << 16);
}

// ---------- prep_x: x -> H0 hi/lo bf16 [256][352] (zero-padded), dcoef[256][4] ----------
__global__ __launch_bounds__(64) void prep_x(const float* __restrict__ x,
                                             u16* __restrict__ hhi, u16* __restrict__ hlo,
                                             float* __restrict__ dcoef)
{
    const int b = blockIdx.x;
    const float* xr = x + (size_t)b * XROW;
    for (int k = threadIdx.x; k < KP0; k += 64) {
        float v = (k < IN_FEAT) ? xr[k] : 0.f;
        u16 hi = f2bf_rne(v);
        u16 lo = f2bf_rne(v - bf2f(hi));
        hhi[(size_t)b * KP0 + k] = hi;
        hlo[(size_t)b * KP0 + k] = lo;
    }
    if (threadIdx.x == 0) {
        float ps = 4.f * xr[IN_FEAT];
        float fl = floorf(ps);
        float mu = ps - fl;
        int i1 = ((int)fl) & 3;
        float mu2 = mu * mu, mu3 = mu2 * mu;
        float c0 = -0.5f * mu3 + mu2 - 0.5f * mu;
        float c1 = 1.5f * mu3 - 2.5f * mu2 + 1.0f;
        float c2 = -1.5f * mu3 + 2.0f * mu2 + 0.5f * mu;
        float c3 = 0.5f * mu3 - 0.5f * mu2;
        float d[4];
        d[(i1 + 3) & 3] = c0;
        d[i1]           = c1;
        d[(i1 + 1) & 3] = c2;
        d[(i1 + 2) & 3] = c3;
        float* dd = dcoef + b * 4;
        dd[0] = d[0]; dd[1] = d[1]; dd[2] = d[2]; dd[3] = d[3];
    }
}

// ---------- prep_w: all three weight tensors -> hi/lo bf16, K/M padded ----------
// chunk = 8 consecutive dst k. W0: rows 4*512, CH=44 ; W1: rows 4*512, CH=64 ; W2: rows 4*320, CH=64
#define C0 (4 * 512 * 44)
#define C1 (4 * 512 * 64)
#define C2 (4 * 320 * 64)

union U8 { u16 u[8]; uint4 v; };

__global__ __launch_bounds__(256) void prep_w(
    const float* __restrict__ W0, const float* __restrict__ W1, const float* __restrict__ W2,
    u16* __restrict__ whi0, u16* __restrict__ wlo0,
    u16* __restrict__ whi1, u16* __restrict__ wlo1,
    u16* __restrict__ whi2, u16* __restrict__ wlo2)
{
    int i = blockIdx.x * 256 + threadIdx.x;
    float src[8];
    u16* dhi; u16* dlo; size_t doff;
    if (i < C0) {
        int row = i / 44, c = i - row * 44;          // row = s*512+o
        int k = c * 8;
#pragma unroll
        for (int j = 0; j < 8; j++) {
            int kk = k + j;
            src[j] = (kk < IN_FEAT) ? W0[(size_t)row * IN_FEAT + kk] : 0.f;
        }
        dhi = whi0; dlo = wlo0; doff = (size_t)row * KP0 + k;
    } else if (i < C0 + C1) {
        int l = i - C0;
        int row = l >> 6, c = l & 63;
        int k = c * 8;
        const float* p = W1 + (size_t)row * HID + k;
#pragma unroll
        for (int j = 0; j < 8; j++) src[j] = p[j];
        dhi = whi1; dlo = wlo1; doff = (size_t)row * HID + k;
    } else if (i < C0 + C1 + C2) {
        int l = i - C0 - C1;
        int row = l >> 6, c = l & 63;                // row = s*320+o
        int k = c * 8;
        int s = row / 320, o = row - s * 320;
        if (o < OUTD) {
            const float* p = W2 + ((size_t)s * OUTD + o) * HID + k;
#pragma unroll
            for (int j = 0; j < 8; j++) src[j] = p[j];
        } else {
#pragma unroll
            for (int j = 0; j < 8; j++) src[j] = 0.f;
        }
        dhi = whi2; dlo = wlo2; doff = (size_t)row * HID + k;
    } else {
        return;
    }
    U8 hi, lo;
#pragma unroll
    for (int j = 0; j < 8; j++) {
        u16 h = f2bf_rne(src[j]);
        hi.u[j] = h;
        lo.u[j] = f2bf_rne(src[j] - bf2f(h));
    }
    *reinterpret_cast<uint4*>(dhi + doff) = hi.v;
    *reinterpret_cast<uint4*>(dlo + doff) = lo.v;
}

// ---------- GEMM: Y[s][b][o] = sum_k W[s][o][k] * H[b][k]  (split-bf16 MFMA) ----------
// grid (N/16, Mp/64, 4); block 256 = 4 waves stacked in o (16 rows each).
// W fragments direct from global; H tile (16 rows x KP, hi+lo) staged once in LDS.
template<int KP, int KLDS>
__global__ __launch_bounds__(256, 2) void gemm_mfma(
    const u16* __restrict__ Whi, const u16* __restrict__ Wlo,
    const u16* __restrict__ Hhi, const u16* __restrict__ Hlo,
    float* __restrict__ Y, int Mp)
{
    __shared__ u16 sHhi[16 * KLDS];
    __shared__ u16 sHlo[16 * KLDS];

    const int tid = (int)threadIdx.x;
    const int b0 = blockIdx.x * 16;
    const int o0 = blockIdx.y * 64;
    const int s  = blockIdx.z;

    // stage H tile: 16 rows x KP bf16 (hi & lo), 16B vectors
    constexpr int CH = KP / 8;
    for (int idx = tid; idx < 16 * CH; idx += 256) {
        int r = idx / CH, c = idx - r * CH;
        size_t g = (size_t)(b0 + r) * KP + c * 8;
        *reinterpret_cast<uint4*>(&sHhi[r * KLDS + c * 8]) =
            *reinterpret_cast<const uint4*>(Hhi + g);
        *reinterpret_cast<uint4*>(&sHlo[r * KLDS + c * 8]) =
            *reinterpret_cast<const uint4*>(Hlo + g);
    }
    __syncthreads();

    const int lane = tid & 63;
    const int wv = tid >> 6;
    const int m = lane & 15;
    const int q = lane >> 4;

    const size_t wrow = ((size_t)s * Mp + o0 + wv * 16 + m) * KP + q * 8;
    const u16* wp_hi = Whi + wrow;
    const u16* wp_lo = Wlo + wrow;
    const u16* hp_hi = &sHhi[m * KLDS + q * 8];
    const u16* hp_lo = &sHlo[m * KLDS + q * 8];

    f32x4 acc0 = {0.f, 0.f, 0.f, 0.f};
    f32x4 acc1 = {0.f, 0.f, 0.f, 0.f};
    f32x4 acc2 = {0.f, 0.f, 0.f, 0.f};

#pragma unroll
    for (int c = 0; c < KP / 32; ++c) {
        bf16x8 ah = *reinterpret_cast<const bf16x8*>(wp_hi + c * 32);
        bf16x8 al = *reinterpret_cast<const bf16x8*>(wp_lo + c * 32);
        bf16x8 bh = *reinterpret_cast<const bf16x8*>(hp_hi + c * 32);
        bf16x8 bl = *reinterpret_cast<const bf16x8*>(hp_lo + c * 32);
        acc0 = __builtin_amdgcn_mfma_f32_16x16x32_bf16(ah, bh, acc0, 0, 0, 0);
        acc1 = __builtin_amdgcn_mfma_f32_16x16x32_bf16(ah, bl, acc1, 0, 0, 0);
        acc2 = __builtin_amdgcn_mfma_f32_16x16x32_bf16(al, bh, acc2, 0, 0, 0);
    }

    f32x4 r = acc0 + acc1 + acc2;
    const int b = b0 + m;                    // C col = lane&15
    const int ob = o0 + wv * 16 + q * 4;     // C row = (lane>>4)*4 + reg
    float* dst = Y + ((size_t)s * BATCH + b) * Mp + ob;
    *reinterpret_cast<float4*>(dst) = make_float4(r[0], r[1], r[2], r[3]);
}

// ---------- blend: v = sum_s d_s*(Y[s][b][o] + bias[s][o]); ELU; emit bf16 hi/lo or fp32 ----
__global__ __launch_bounds__(256) void blend(
    const float* __restrict__ Y, const float* __restrict__ bias,
    const float* __restrict__ dcoef, int M, int Mp, int mode,
    u16* __restrict__ hhi, u16* __restrict__ hlo, float* __restrict__ out)
{
    const int b = blockIdx.x;
    const float d0 = dcoef[b * 4 + 0];
    const float d1 = dcoef[b * 4 + 1];
    const float d2 = dcoef[b * 4 + 2];
    const float d3 = dcoef[b * 4 + 3];
    const float* yb = Y + (size_t)b * Mp;
    const size_t plane = (size_t)BATCH * Mp;

    for (int o = (int)threadIdx.x; o < M; o += 256) {
        float v = d0 * (yb[0 * plane + o] + bias[0 * M + o])
                + d1 * (yb[1 * plane + o] + bias[1 * M + o])
                + d2 * (yb[2 * plane + o] + bias[2 * M + o])
                + d3 * (yb[3 * plane + o] + bias[3 * M + o]);
        if (mode) {
            v = (v > 0.f) ? v : expm1f(v);
            u16 hi = f2bf_rne(v);
            hhi[(size_t)b * M + o] = hi;
            hlo[(size_t)b * M + o] = f2bf_rne(v - bf2f(hi));
        } else {
            out[(size_t)b * M + o] = v;
        }
    }
}

extern "C" void kernel_launch(void* const* d_in, const int* in_sizes, int n_in,
                              void* d_out, int out_size, void* d_ws, size_t ws_size,
                              hipStream_t stream) {
    const float* x  = (const float*)d_in[0];
    const float* W0 = (const float*)d_in[1];
    const float* b0 = (const float*)d_in[2];
    const float* W1 = (const float*)d_in[3];
    const float* b1 = (const float*)d_in[4];
    const float* W2 = (const float*)d_in[5];
    const float* b2 = (const float*)d_in[6];
    float* out = (float*)d_out;

    char* p = (char*)d_ws;
    auto alloc = [&](size_t bytes) { char* r = p; p += (bytes + 255) & ~(size_t)255; return r; };

    float* dcoef = (float*)alloc(BATCH * 4 * sizeof(float));
    float* Y     = (float*)alloc((size_t)4 * BATCH * HID * sizeof(float));
    u16* whi0 = (u16*)alloc((size_t)4 * HID * KP0 * 2);
    u16* wlo0 = (u16*)alloc((size_t)4 * HID * KP0 * 2);
    u16* whi1 = (u16*)alloc((size_t)4 * HID * HID * 2);
    u16* wlo1 = (u16*)alloc((size_t)4 * HID * HID * 2);
    u16* whi2 = (u16*)alloc((size_t)4 * MP2 * HID * 2);
    u16* wlo2 = (u16*)alloc((size_t)4 * MP2 * HID * 2);
    u16* h0hi = (u16*)alloc((size_t)BATCH * KP0 * 2);
    u16* h0lo = (u16*)alloc((size_t)BATCH * KP0 * 2);
    u16* hahi = (u16*)alloc((size_t)BATCH * HID * 2);
    u16* halo = (u16*)alloc((size_t)BATCH * HID * 2);
    u16* hbhi = (u16*)alloc((size_t)BATCH * HID * 2);
    u16* hblo = (u16*)alloc((size_t)BATCH * HID * 2);

    prep_x<<<dim3(BATCH), 64, 0, stream>>>(x, h0hi, h0lo, dcoef);
    {
        int tot = C0 + C1 + C2;
        prep_w<<<dim3((tot + 255) / 256), 256, 0, stream>>>(
            W0, W1, W2, whi0, wlo0, whi1, wlo1, whi2, wlo2);
    }

    // layer 0: K=352pad, M=512
    gemm_mfma<KP0, KP0 + 8><<<dim3(BATCH / 16, HID / 64, 4), 256, 0, stream>>>(
        whi0, wlo0, h0hi, h0lo, Y, HID);
    blend<<<dim3(BATCH), 256, 0, stream>>>(Y, b0, dcoef, HID, HID, 1, hahi, halo, nullptr);

    // layer 1: K=512, M=512
    gemm_mfma<HID, HID + 8><<<dim3(BATCH / 16, HID / 64, 4), 256, 0, stream>>>(
        whi1, wlo1, hahi, halo, Y, HID);
    blend<<<dim3(BATCH), 256, 0, stream>>>(Y, b1, dcoef, HID, HID, 1, hbhi, hblo, nullptr);

    // layer 2: K=512, M=320pad
    gemm_mfma<HID, HID + 8><<<dim3(BATCH / 16, MP2 / 64, 4), 256, 0, stream>>>(
        whi2, wlo2, hbhi, hblo, Y, MP2);
    blend<<<dim3(BATCH), 256, 0, stream>>>(Y, b2, dcoef, OUTD, MP2, 0, nullptr, nullptr, out);
}